// Round 18
// baseline (798.628 us; speedup 1.0000x reference)
//
#include <hip/hip_runtime.h>
#include <hip/hip_bf16.h>

constexpr int N  = 50000;
constexpr int M  = 800000;
constexpr int D  = 128;
constexpr int IN = 192;   // D + EF + DF
constexpr int TE = 128;   // edges per block (edge kernel)
constexpr int NCH = 20;   // 8KB weight chunks per layer
constexpr int NBLK = (N + 255) / 256;   // scan blocks

typedef __attribute__((ext_vector_type(4)))  short short4v;
typedef __attribute__((ext_vector_type(8)))  short short8;
typedef __attribute__((ext_vector_type(16))) float f32x16;
typedef _Float16 half8  __attribute__((ext_vector_type(8)));

// packed fp16 edge weights: 2 layers x 20 chunks x 512 short8
__device__ __align__(16) short g_wp[163840];
// packed bf16 LSTM weights
__device__ __align__(16) short g_lw[262144];
// packed fp16 [ef|df] rows, in SORTED edge order: M x 64
__device__ __align__(16) short g_efdf[(size_t)M * 64];
// fp16 shadow of state (edge-input view), rewritten per layer
__device__ __align__(16) short g_sbf[(size_t)N * D];
// sort machinery
__device__ int g_cnt[N];       // histogram -> exclusive offsets -> scatter cursors
__device__ int g_part[NBLK];   // scan partials
__device__ int g_ssrc[M];      // src, sorted by dst
__device__ int g_sdst[M];      // dst, sorted

__device__ __forceinline__ float sigm(float x) { return 1.0f / (1.0f + __expf(-x)); }

// lgkm-only barrier: LDS visibility WITHOUT draining outstanding global loads/atomics
__device__ __forceinline__ void barrier_lgkm() {
    asm volatile("s_waitcnt lgkmcnt(0)" ::: "memory");
    __builtin_amdgcn_s_barrier();
}

__device__ __forceinline__ short f2bf(float f) {
    unsigned u = __builtin_bit_cast(unsigned, f);
    u = (u + 0x7FFFu + ((u >> 16) & 1u)) >> 16;   // RNE
    return (short)u;
}
// bf16 pair pack (LSTM path)
__device__ __forceinline__ unsigned pk2(float a, float b) {
    __hip_bfloat162 h = __float22bfloat162_rn(float2{a, b});
    unsigned u;
    __builtin_memcpy(&u, &h, 4);
    return u;
}
// fp16 pair pack: v_cvt_pkrtz_f16_f32 (1 op)
__device__ __forceinline__ unsigned pkh(float a, float b) {
    auto h = __builtin_amdgcn_cvt_pkrtz(a, b);
    unsigned u;
    __builtin_memcpy(&u, &h, 4);
    return u;
}
__device__ __forceinline__ short f2h(float f) {
    _Float16 h = (_Float16)f;
    return __builtin_bit_cast(short, h);
}
__device__ __forceinline__ float h2f(short s) {
    _Float16 h = __builtin_bit_cast(_Float16, s);
    return (float)h;
}

// ---------------- sort-by-dst (counting sort, per call) ----------------
__global__ void hist_kernel(const int* __restrict__ edge) {
    int e = blockIdx.x * 256 + threadIdx.x;
    if (e < M) atomicAdd(&g_cnt[edge[e * 2 + 1]], 1);
}
__global__ void scanA_kernel() {   // block sums
    __shared__ int red[256];
    const int t = threadIdx.x;
    const int idx = blockIdx.x * 256 + t;
    red[t] = (idx < N) ? g_cnt[idx] : 0;
    __syncthreads();
#pragma unroll
    for (int s = 128; s > 0; s >>= 1) {
        if (t < s) red[t] += red[t + s];
        __syncthreads();
    }
    if (t == 0) g_part[blockIdx.x] = red[0];
}
__global__ void scanB_kernel() {   // 1 block: exclusive scan of partials
    __shared__ int sh[256];
    const int t = threadIdx.x;
    int v = (t < NBLK) ? g_part[t] : 0;
    sh[t] = v;
    __syncthreads();
    int x = v;
    for (int s = 1; s < 256; s <<= 1) {
        int y = (t >= s) ? sh[t - s] : 0;
        __syncthreads();
        x += y; sh[t] = x;
        __syncthreads();
    }
    if (t < NBLK) g_part[t] = x - v;
}
__global__ void scanC_kernel() {   // per-block exclusive scan + base
    __shared__ int sh[256];
    const int t = threadIdx.x;
    const int idx = blockIdx.x * 256 + t;
    int v = (idx < N) ? g_cnt[idx] : 0;
    sh[t] = v;
    __syncthreads();
    int x = v;
    for (int s = 1; s < 256; s <<= 1) {
        int y = (t >= s) ? sh[t - s] : 0;
        __syncthreads();
        x += y; sh[t] = x;
        __syncthreads();
    }
    if (idx < N) g_cnt[idx] = g_part[blockIdx.x] + x - v;
}
// scatter + fused ef/df fp16 pack into sorted position
__global__ void scatter_kernel(const int* __restrict__ edge,
                               const float* __restrict__ ef, const float* __restrict__ df) {
    int e = blockIdx.x * 256 + threadIdx.x;
    if (e < M) {
        const int s = edge[e * 2], d = edge[e * 2 + 1];
        const int p = atomicAdd(&g_cnt[d], 1);
        g_ssrc[p] = s;
        g_sdst[p] = d;
        const float4* ar = (const float4*)(ef + (size_t)e * 32);
        const float4* br = (const float4*)(df + (size_t)e * 32);
        short8* dst = (short8*)(g_efdf + (size_t)p * 64);
#pragma unroll
        for (int i = 0; i < 4; ++i) {
            float4 u0 = ar[i * 2], u1 = ar[i * 2 + 1];
            short8 t;
            unsigned* tp = (unsigned*)&t;
            tp[0] = pkh(u0.x, u0.y); tp[1] = pkh(u0.z, u0.w);
            tp[2] = pkh(u1.x, u1.y); tp[3] = pkh(u1.z, u1.w);
            dst[i] = t;
        }
#pragma unroll
        for (int i = 0; i < 4; ++i) {
            float4 u0 = br[i * 2], u1 = br[i * 2 + 1];
            short8 t;
            unsigned* tp = (unsigned*)&t;
            tp[0] = pkh(u0.x, u0.y); tp[1] = pkh(u0.z, u0.w);
            tp[2] = pkh(u1.x, u1.y); tp[3] = pkh(u1.z, u1.w);
            dst[4 + i] = t;
        }
    }
}

// ---------------- fused prep: zero g_cnt + pack edge/LSTM weights + init state/shadow/msg ----------------
__global__ void prep_static(const float* __restrict__ w0m, const float* __restrict__ w0a,
                            const float* __restrict__ w1m, const float* __restrict__ w1a,
                            const float* __restrict__ wih, const float* __restrict__ whh,
                            const float4* __restrict__ nf, const float4* __restrict__ nfc,
                            float4* __restrict__ state, float4* __restrict__ state_c,
                            float4* __restrict__ msg) {
    const int gid = blockIdx.x * 256 + threadIdx.x;    // grid = 1024*256 = 262144

    // task 1: zero histogram
    if (gid < N) g_cnt[gid] = 0;

    // task 2: pack edge weights (163840 elems)
    if (gid < 163840) {
        int ii = gid / 81920;
        int r  = gid % 81920;
        int p  = r / 40960;  r %= 40960;
        int which = (r >= 24576) ? 1 : 0;
        int r2 = which ? r - 24576 : r;
        int e    = r2 & 7;
        int f    = r2 >> 3;
        int lane = f & 63;
        int ktct = f >> 6;
        int ct = ktct & 3, kt = ktct >> 2;
        int k   = kt * 16 + ((lane >> 5) << 3) + e;
        int col = ct * 32 + (lane & 31);
        const float* w0 = p ? w0a : w0m;
        const float* w1 = p ? w1a : w1m;
        float v = which ? w1[((size_t)ii * D + k) * D + col]
                        : w0[((size_t)ii * IN + k) * D + col];
        g_wp[gid] = f2h(v);
    }

    // task 3: pack LSTM weights (262144 elems)
    {
        int ii = gid >> 17;
        int r  = gid & 131071;
        int e = r & 7, f = r >> 3;
        int lane = f & 63, rest = f >> 6;
        int cf = rest & 15, kt = rest >> 4;
        int col = cf * 32 + (lane & 31);
        int k   = (kt & 7) * 16 + ((lane >> 5) << 3) + e;
        const float* src = (kt < 8) ? wih : whh;
        g_lw[gid] = f2bf(src[((size_t)ii * 512 + col) * D + k]);
    }

    // task 4: init state/state_c/shadow/msg (grid-stride, N*D/4 = 1.6M float4)
    const int total = N * D / 4;
    const float4 z = make_float4(0.f, 0.f, 0.f, 0.f);
    for (int i = gid; i < total; i += 262144) {
        float4 v = nf[i];
        state[i]   = v;
        state_c[i] = nfc[i];
        short4v b;
        unsigned* bp = (unsigned*)&b;
        bp[0] = pkh(v.x, v.y); bp[1] = pkh(v.z, v.w);
        *(short4v*)(g_sbf + (size_t)i * 4) = b;
        msg[i] = z;
    }
}

// ---------------- edge kernel: 8KB-chunk 2-deep prefetch fp16 pipeline, 512 threads ----------------
#define MFMA16(a, b, c) __builtin_amdgcn_mfma_f32_32x32x16_f16(a, b, c, 0, 0, 0)
#define MFMABF(a, b, c) __builtin_amdgcn_mfma_f32_32x32x16_bf16(a, b, c, 0, 0, 0)

template<int BASE, int NC, bool FROM_H>
__device__ __forceinline__ void gemm_phase(const short8* __restrict__ gsrc, short8* wb,
                                           short8& gA, const half8 a1[12],
                                           const short (*hsr)[136],
                                           int tid, int lane, int cg, int half,
                                           f32x16& o0, f32x16& o1) {
    f32x16 acc0 = {}, acc1 = {};
#pragma unroll
    for (int c = 0; c < NC; ++c) {
        const int gc = BASE + c;
        short8 gB;
        if (gc + 2 < NCH) gB = gsrc[(size_t)(gc + 2) * 512 + tid];
        const short8* buf = wb + (gc & 1) * 512;
        __builtin_amdgcn_s_setprio(1);
#pragma unroll
        for (int kl = 0; kl < 2; ++kl) {
            const int kt = c * 2 + kl;
            half8 a = FROM_H
                ? __builtin_bit_cast(half8, *(const short8*)&hsr[lane & 31][kt * 16 + half])
                : a1[kt];
            half8 b0 = __builtin_bit_cast(half8, buf[(kl * 4 + cg * 2 + 0) * 64 + lane]);
            half8 b1 = __builtin_bit_cast(half8, buf[(kl * 4 + cg * 2 + 1) * 64 + lane]);
            acc0 = MFMA16(a, b0, acc0);
            acc1 = MFMA16(a, b1, acc1);
        }
        __builtin_amdgcn_s_setprio(0);
        if (gc + 1 < NCH) wb[((gc + 1) & 1) * 512 + tid] = gA;
        barrier_lgkm();
        if (gc + 2 < NCH) gA = gB;
    }
    o0 = acc0; o1 = acc1;
}

__device__ __forceinline__ void hwrite(short (*hsr)[136], const f32x16& a0, const f32x16& a1v,
                                       const float* __restrict__ b0, int lane, int cg) {
#pragma unroll
    for (int ct = 0; ct < 2; ++ct) {
        const int col = cg * 64 + ct * 32 + (lane & 31);
        const float bv = b0[col];
        f32x16 a = ct ? a1v : a0;
#pragma unroll
        for (int rp = 0; rp < 8; ++rp) {
            const int reg = rp * 2;
            const int row = (reg & 3) + 8 * (reg >> 2) + 4 * (lane >> 5);
            const unsigned pr = pkh(fmaxf(a[reg] + bv, 0.f), fmaxf(a[reg + 1] + bv, 0.f));
            hsr[row][col]     = (short)(pr & 0xFFFF);
            hsr[row + 1][col] = (short)(pr >> 16);
        }
    }
}

__global__ __launch_bounds__(512, 4)
void edge_mfma(int ii,
               const float* __restrict__ b0m, const float* __restrict__ b1m,
               const float* __restrict__ b0a, const float* __restrict__ b1a,
               float* __restrict__ state_msg) {
    __shared__ __align__(16) char pool[51712];
    short8* wb = (short8*)pool;
    short (*hs)[32][136] = (short(*)[32][136])(pool + 16384);
    int* sdst = (int*)(pool + 51200);

    const int tid  = threadIdx.x;
    const int lane = tid & 63;
    const int w    = tid >> 6;          // 0..7
    const int rt   = w >> 1;            // 0..3  (32-edge group)
    const int cg   = w & 1;             // 0..1  (64-col group)
    const int e0   = blockIdx.x * TE;

    if (tid < TE) sdst[tid] = g_sdst[e0 + tid];

    const int er   = e0 + rt * 32 + (lane & 31);
    const int half = (lane >> 5) << 3;
    const int s  = g_ssrc[er];
    const int d2 = g_sdst[er];
    const short* srow = g_sbf + (size_t)s  * D;
    const short* drow = g_sbf + (size_t)d2 * D;
    half8 a1[12];
#pragma unroll
    for (int kt = 0; kt < 8; ++kt) {
        const int k0 = kt * 16 + half;
        half8 sv = __builtin_bit_cast(half8, *(const short8*)(srow + k0));
        half8 dv = __builtin_bit_cast(half8, *(const short8*)(drow + k0));
        a1[kt] = sv - dv;
    }
#pragma unroll
    for (int kt = 8; kt < 12; ++kt)
        a1[kt] = __builtin_bit_cast(half8, *(const short8*)(g_efdf + (size_t)er * 64 + (kt - 8) * 16 + half));

    const short8* gsrc = (const short8*)(g_wp + (size_t)ii * 81920);

    wb[tid] = gsrc[tid];
    short8 gA = gsrc[512 + tid];
    barrier_lgkm();

    f32x16 t0, t1, m0, m1, c0, c1;
    gemm_phase<0, 6, false>(gsrc, wb, gA, a1, hs[rt], tid, lane, cg, half, t0, t1);
    hwrite(hs[rt], t0, t1, b0m, lane, cg);
    barrier_lgkm();
    gemm_phase<6, 4, true>(gsrc, wb, gA, a1, hs[rt], tid, lane, cg, half, m0, m1);

    unsigned mb[16];
#pragma unroll
    for (int ct = 0; ct < 2; ++ct) {
        const float bm = b1m[cg * 64 + ct * 32 + (lane & 31)];
        f32x16 mv = ct ? m1 : m0;
#pragma unroll
        for (int rp = 0; rp < 8; ++rp)
            mb[ct * 8 + rp] = pkh(mv[rp * 2] + bm, mv[rp * 2 + 1] + bm);
    }

    gemm_phase<10, 6, false>(gsrc, wb, gA, a1, hs[rt], tid, lane, cg, half, t0, t1);
    hwrite(hs[rt], t0, t1, b0a, lane, cg);
    barrier_lgkm();
    gemm_phase<16, 4, true>(gsrc, wb, gA, a1, hs[rt], tid, lane, cg, half, c0, c1);

    float (*vt)[132] = (float(*)[132])pool;
    const int colr = tid & 127;
    const int sub  = tid >> 7;
#pragma unroll
    for (int pass = 0; pass < 2; ++pass) {
        if ((rt >> 1) == pass) {
#pragma unroll
            for (int ct = 0; ct < 2; ++ct) {
                const int col = cg * 64 + ct * 32 + (lane & 31);
                const float ba = b1a[col];
                f32x16 av = ct ? c1 : c0;
#pragma unroll
                for (int rp = 0; rp < 8; ++rp) {
                    const int reg = rp * 2;
                    const unsigned u = mb[ct * 8 + rp];
                    const int row = (rt & 1) * 32 + (reg & 3) + 8 * (reg >> 2) + 4 * (lane >> 5);
                    vt[row][col]     = h2f((short)(u & 0xFFFF)) * sigm(av[reg] + ba);
                    vt[row + 1][col] = h2f((short)(u >> 16))    * sigm(av[reg + 1] + ba);
                }
            }
        }
        barrier_lgkm();
        const int gbase = pass * 64 + sub * 16;
        float run = 0.f;
        int cur = sdst[gbase];
#pragma unroll 4
        for (int r = 0; r < 16; ++r) {
            const int dd = sdst[gbase + r];
            if (dd != cur) {
                atomicAdd(state_msg + (size_t)cur * D + colr, run);
                run = 0.f; cur = dd;
            }
            run += vt[sub * 16 + r][colr];
        }
        atomicAdd(state_msg + (size_t)cur * D + colr, run);
        barrier_lgkm();
    }
}

// ---------------- LSTM: bf16 MFMA; lgkm inner barriers; final __syncthreads guards x-zeroing ----------------
__global__ __launch_bounds__(256, 4)
void lstm_mfma(float* __restrict__ x, float* __restrict__ hbuf, float* __restrict__ cbuf,
               int ii, int last,
               const float* __restrict__ bih, const float* __restrict__ bhh) {
    __shared__ short8 wb[2048];
    const int tid  = threadIdx.x;
    const int lane = tid & 63;
    const int w    = tid >> 6;
    const int n0   = blockIdx.x * 32;
    const int half = (lane >> 5) << 3;
    const int nl   = lane & 31;
    const int nld  = min(n0 + nl, N - 1);

    const short8* gsrc = (const short8*)(g_lw + (size_t)ii * 131072);

    {
        short8 g[4];
#pragma unroll
        for (int i = 0; i < 4; ++i) g[i] = gsrc[tid + i * 256];
#pragma unroll
        for (int i = 0; i < 4; ++i) wb[tid + i * 256] = g[i];
        barrier_lgkm();
    }

    f32x16 acc[4] = {};
#pragma unroll
    for (int kt = 0; kt < 16; ++kt) {
        const float* srow = (kt < 8) ? (x + (size_t)nld * D + kt * 16 + half)
                                     : (hbuf + (size_t)nld * D + (kt - 8) * 16 + half);
        float4 u0 = *(const float4*)(srow);
        float4 u1 = *(const float4*)(srow + 4);
        short8 a;
        unsigned* ap = (unsigned*)&a;
        ap[0] = pk2(u0.x, u0.y); ap[1] = pk2(u0.z, u0.w);
        ap[2] = pk2(u1.x, u1.y); ap[3] = pk2(u1.z, u1.w);

        short8 g[4];
        if (kt + 1 < 16) {
            const short8* p = gsrc + (size_t)(kt + 1) * 1024;
#pragma unroll
            for (int i = 0; i < 4; ++i) g[i] = p[tid + i * 256];
        }
        const short8* buf = wb + (kt & 1) * 1024;
        __builtin_amdgcn_s_setprio(1);
#pragma unroll
        for (int q = 0; q < 4; ++q) {
            short8 b = buf[(q * 4 + w) * 64 + lane];
            acc[q] = MFMABF(a, b, acc[q]);
        }
        __builtin_amdgcn_s_setprio(0);
        if (kt + 1 < 16) {
            short8* d = wb + ((kt + 1) & 1) * 1024;
#pragma unroll
            for (int i = 0; i < 4; ++i) d[tid + i * 256] = g[i];
            barrier_lgkm();
        } else {
            __syncthreads();   // final: full drain before x-zeroing below
        }
    }

    const int col = (w << 5) + nl;
    const float bi = bih[col]       + bhh[col];
    const float bf = bih[128 + col] + bhh[128 + col];
    const float bg = bih[256 + col] + bhh[256 + col];
    const float bo = bih[384 + col] + bhh[384 + col];
#pragma unroll
    for (int reg = 0; reg < 16; ++reg) {
        const int nn = (reg & 3) + 8 * (reg >> 2) + 4 * (lane >> 5);
        const int n = n0 + nn;
        if (n < N) {
            const float gi = acc[0][reg] + bi;
            const float gf = acc[1][reg] + bf;
            const float gg = acc[2][reg] + bg;
            const float go = acc[3][reg] + bo;
            float* cp = cbuf + (size_t)n * D + col;
            const float c2 = sigm(gf) * (*cp) + sigm(gi) * tanhf(gg);
            const float h2 = sigm(go) * tanhf(c2);
            *cp = c2;
            const float ho = last ? h2 : fmaxf(h2, 0.f);
            hbuf[(size_t)n * D + col] = ho;
            if (!last) g_sbf[(size_t)n * D + col] = f2h(ho);
        }
    }

    if (!last) {
        float4* xr = (float4*)(x + (size_t)n0 * D);
        const float4 z = make_float4(0.f, 0.f, 0.f, 0.f);
#pragma unroll
        for (int i = 0; i < 4; ++i) {
            const int idx = tid + i * 256;
            if (n0 + (idx >> 5) < N) xr[idx] = z;
        }
    }
}

extern "C" void kernel_launch(void* const* d_in, const int* in_sizes, int n_in,
                              void* d_out, int out_size, void* d_ws, size_t ws_size,
                              hipStream_t stream) {
    const float* node_feat   = (const float*)d_in[0];
    const float* node_feat_c = (const float*)d_in[1];
    const int*   edge        = (const int*)d_in[2];
    const float* edge_feat   = (const float*)d_in[3];
    const float* dist_feat   = (const float*)d_in[4];
    const float* msg_w0 = (const float*)d_in[5];
    const float* msg_b0 = (const float*)d_in[6];
    const float* msg_w1 = (const float*)d_in[7];
    const float* msg_b1 = (const float*)d_in[8];
    const float* att_w0 = (const float*)d_in[9];
    const float* att_b0 = (const float*)d_in[10];
    const float* att_w1 = (const float*)d_in[11];
    const float* att_b1 = (const float*)d_in[12];
    const float* lstm_wih = (const float*)d_in[13];
    const float* lstm_whh = (const float*)d_in[14];
    const float* lstm_bih = (const float*)d_in[15];
    const float* lstm_bhh = (const float*)d_in[16];

    float* state     = (float*)d_out;
    float* state_c   = (float*)d_ws;
    float* state_msg = (float*)d_ws + (size_t)N * D;

    // fused prep: zero hist + pack weights + init state/shadow/msg
    prep_static<<<1024, 256, 0, stream>>>(msg_w0, att_w0, msg_w1, att_w1, lstm_wih, lstm_whh,
                                          (const float4*)node_feat, (const float4*)node_feat_c,
                                          (float4*)state, (float4*)state_c, (float4*)state_msg);

    // sort edges by dst; scatter also packs ef/df
    hist_kernel<<<(M + 255) / 256, 256, 0, stream>>>(edge);
    scanA_kernel<<<NBLK, 256, 0, stream>>>();
    scanB_kernel<<<1, 256, 0, stream>>>();
    scanC_kernel<<<NBLK, 256, 0, stream>>>();
    scatter_kernel<<<(M + 255) / 256, 256, 0, stream>>>(edge, edge_feat, dist_feat);

    for (int ii = 0; ii < 2; ++ii) {
        edge_mfma<<<M / TE, 512, 0, stream>>>(
            ii,
            msg_b0 + (size_t)ii * D, msg_b1 + (size_t)ii * D,
            att_b0 + (size_t)ii * D, att_b1 + (size_t)ii * D,
            state_msg);

        lstm_mfma<<<(N + 31) / 32, 256, 0, stream>>>(
            state_msg, state, state_c, ii, (ii == 1) ? 1 : 0,
            lstm_bih + (size_t)ii * 4 * D, lstm_bhh + (size_t)ii * 4 * D);
    }
}

// Round 19
// 787.426 us; speedup vs baseline: 1.0142x; 1.0142x over previous
//
#include <hip/hip_runtime.h>
#include <hip/hip_bf16.h>

constexpr int N  = 50000;
constexpr int M  = 800000;
constexpr int D  = 128;
constexpr int IN = 192;   // D + EF + DF
constexpr int TE = 128;   // edges per block (edge kernel)
constexpr int NCH = 20;   // 8KB weight chunks per layer
constexpr int NBLK = (N + 255) / 256;   // scan blocks

typedef __attribute__((ext_vector_type(4)))  short short4v;
typedef __attribute__((ext_vector_type(8)))  short short8;
typedef __attribute__((ext_vector_type(16))) float f32x16;
typedef _Float16 half8  __attribute__((ext_vector_type(8)));

// packed fp16 edge weights: 2 layers x 20 chunks x 512 short8
__device__ __align__(16) short g_wp[163840];
// packed bf16 LSTM weights
__device__ __align__(16) short g_lw[262144];
// packed fp16 [ef|df] rows, in SORTED edge order: M x 64
__device__ __align__(16) short g_efdf[(size_t)M * 64];
// fp16 shadow of state (edge-input view), rewritten per layer
__device__ __align__(16) short g_sbf[(size_t)N * D];
// sort machinery
__device__ int g_cnt[N];       // histogram -> exclusive offsets -> scatter cursors
__device__ int g_part[NBLK];   // scan partials
__device__ int g_ssrc[M];      // src, sorted by dst
__device__ int g_sdst[M];      // dst, sorted

__device__ __forceinline__ float sigm(float x) { return 1.0f / (1.0f + __expf(-x)); }

// lgkm-only barrier: LDS visibility WITHOUT draining outstanding global loads/atomics
__device__ __forceinline__ void barrier_lgkm() {
    asm volatile("s_waitcnt lgkmcnt(0)" ::: "memory");
    __builtin_amdgcn_s_barrier();
}

__device__ __forceinline__ short f2bf(float f) {
    unsigned u = __builtin_bit_cast(unsigned, f);
    u = (u + 0x7FFFu + ((u >> 16) & 1u)) >> 16;   // RNE
    return (short)u;
}
// bf16 pair pack (LSTM path)
__device__ __forceinline__ unsigned pk2(float a, float b) {
    __hip_bfloat162 h = __float22bfloat162_rn(float2{a, b});
    unsigned u;
    __builtin_memcpy(&u, &h, 4);
    return u;
}
// fp16 pair pack: v_cvt_pkrtz_f16_f32 (1 op)
__device__ __forceinline__ unsigned pkh(float a, float b) {
    auto h = __builtin_amdgcn_cvt_pkrtz(a, b);
    unsigned u;
    __builtin_memcpy(&u, &h, 4);
    return u;
}
__device__ __forceinline__ short f2h(float f) {
    _Float16 h = (_Float16)f;
    return __builtin_bit_cast(short, h);
}
__device__ __forceinline__ float h2f(short s) {
    _Float16 h = __builtin_bit_cast(_Float16, s);
    return (float)h;
}

// ---------------- sort-by-dst (counting sort, per call) ----------------
__global__ void hist_kernel(const int* __restrict__ edge) {
    int e = blockIdx.x * 256 + threadIdx.x;
    if (e < M) atomicAdd(&g_cnt[edge[e * 2 + 1]], 1);
}
__global__ void scanA_kernel() {   // block sums
    __shared__ int red[256];
    const int t = threadIdx.x;
    const int idx = blockIdx.x * 256 + t;
    red[t] = (idx < N) ? g_cnt[idx] : 0;
    __syncthreads();
#pragma unroll
    for (int s = 128; s > 0; s >>= 1) {
        if (t < s) red[t] += red[t + s];
        __syncthreads();
    }
    if (t == 0) g_part[blockIdx.x] = red[0];
}
__global__ void scanB_kernel() {   // 1 block: exclusive scan of partials
    __shared__ int sh[256];
    const int t = threadIdx.x;
    int v = (t < NBLK) ? g_part[t] : 0;
    sh[t] = v;
    __syncthreads();
    int x = v;
    for (int s = 1; s < 256; s <<= 1) {
        int y = (t >= s) ? sh[t - s] : 0;
        __syncthreads();
        x += y; sh[t] = x;
        __syncthreads();
    }
    if (t < NBLK) g_part[t] = x - v;
}
__global__ void scanC_kernel() {   // per-block exclusive scan + base
    __shared__ int sh[256];
    const int t = threadIdx.x;
    const int idx = blockIdx.x * 256 + t;
    int v = (idx < N) ? g_cnt[idx] : 0;
    sh[t] = v;
    __syncthreads();
    int x = v;
    for (int s = 1; s < 256; s <<= 1) {
        int y = (t >= s) ? sh[t - s] : 0;
        __syncthreads();
        x += y; sh[t] = x;
        __syncthreads();
    }
    if (idx < N) g_cnt[idx] = g_part[blockIdx.x] + x - v;
}
// scatter + fused ef/df fp16 pack into sorted position
__global__ void scatter_kernel(const int* __restrict__ edge,
                               const float* __restrict__ ef, const float* __restrict__ df) {
    int e = blockIdx.x * 256 + threadIdx.x;
    if (e < M) {
        const int s = edge[e * 2], d = edge[e * 2 + 1];
        const int p = atomicAdd(&g_cnt[d], 1);
        g_ssrc[p] = s;
        g_sdst[p] = d;
        const float4* ar = (const float4*)(ef + (size_t)e * 32);
        const float4* br = (const float4*)(df + (size_t)e * 32);
        short8* dst = (short8*)(g_efdf + (size_t)p * 64);
#pragma unroll
        for (int i = 0; i < 4; ++i) {
            float4 u0 = ar[i * 2], u1 = ar[i * 2 + 1];
            short8 t;
            unsigned* tp = (unsigned*)&t;
            tp[0] = pkh(u0.x, u0.y); tp[1] = pkh(u0.z, u0.w);
            tp[2] = pkh(u1.x, u1.y); tp[3] = pkh(u1.z, u1.w);
            dst[i] = t;
        }
#pragma unroll
        for (int i = 0; i < 4; ++i) {
            float4 u0 = br[i * 2], u1 = br[i * 2 + 1];
            short8 t;
            unsigned* tp = (unsigned*)&t;
            tp[0] = pkh(u0.x, u0.y); tp[1] = pkh(u0.z, u0.w);
            tp[2] = pkh(u1.x, u1.y); tp[3] = pkh(u1.z, u1.w);
            dst[4 + i] = t;
        }
    }
}

// ---------------- fused prep: zero g_cnt + pack edge weights + pack LSTM weights ----------------
__global__ void prep_static(const float* __restrict__ w0m, const float* __restrict__ w0a,
                            const float* __restrict__ w1m, const float* __restrict__ w1a,
                            const float* __restrict__ wih, const float* __restrict__ whh) {
    const int gid = blockIdx.x * 256 + threadIdx.x;    // grid = 1024*256 = 262144

    // task 1: zero histogram
    if (gid < N) g_cnt[gid] = 0;

    // task 2: pack edge weights (163840 elems)
    if (gid < 163840) {
        int ii = gid / 81920;
        int r  = gid % 81920;
        int p  = r / 40960;  r %= 40960;
        int which = (r >= 24576) ? 1 : 0;
        int r2 = which ? r - 24576 : r;
        int e    = r2 & 7;
        int f    = r2 >> 3;
        int lane = f & 63;
        int ktct = f >> 6;
        int ct = ktct & 3, kt = ktct >> 2;
        int k   = kt * 16 + ((lane >> 5) << 3) + e;
        int col = ct * 32 + (lane & 31);
        const float* w0 = p ? w0a : w0m;
        const float* w1 = p ? w1a : w1m;
        float v = which ? w1[((size_t)ii * D + k) * D + col]
                        : w0[((size_t)ii * IN + k) * D + col];
        g_wp[gid] = f2h(v);
    }

    // task 3: pack LSTM weights (262144 elems)
    {
        int ii = gid >> 17;
        int r  = gid & 131071;
        int e = r & 7, f = r >> 3;
        int lane = f & 63, rest = f >> 6;
        int cf = rest & 15, kt = rest >> 4;
        int col = cf * 32 + (lane & 31);
        int k   = (kt & 7) * 16 + ((lane >> 5) << 3) + e;
        const float* src = (kt < 8) ? wih : whh;
        g_lw[gid] = f2bf(src[((size_t)ii * 512 + col) * D + k]);
    }
}

// ---------------- init: state/state_c copy + fp16 shadow + zero msg ----------------
__global__ void init_kernel(const float4* __restrict__ nf, const float4* __restrict__ nfc,
                            float4* __restrict__ state, float4* __restrict__ state_c,
                            float4* __restrict__ msg) {
    const int total = N * D / 4;
    const float4 z = make_float4(0.f, 0.f, 0.f, 0.f);
    for (int i = blockIdx.x * blockDim.x + threadIdx.x; i < total; i += gridDim.x * blockDim.x) {
        float4 v = nf[i];
        state[i]   = v;
        state_c[i] = nfc[i];
        short4v b;
        unsigned* bp = (unsigned*)&b;
        bp[0] = pkh(v.x, v.y); bp[1] = pkh(v.z, v.w);
        *(short4v*)(g_sbf + (size_t)i * 4) = b;
        msg[i] = z;
    }
}

// ---------------- edge kernel: 8KB-chunk 2-deep prefetch fp16 pipeline, 512 threads ----------------
#define MFMA16(a, b, c) __builtin_amdgcn_mfma_f32_32x32x16_f16(a, b, c, 0, 0, 0)
#define MFMABF(a, b, c) __builtin_amdgcn_mfma_f32_32x32x16_bf16(a, b, c, 0, 0, 0)

// chunk = 512 short8 (8 KB) = 2 kt. chunk gc: issue load(gc+2) -> [setprio(1) MFMA cluster setprio(0)]
// -> store held(gc+1) -> lgkm barrier
template<int BASE, int NC, bool FROM_H>
__device__ __forceinline__ void gemm_phase(const short8* __restrict__ gsrc, short8* wb,
                                           short8& gA, const half8 a1[12],
                                           const short (*hsr)[136],
                                           int tid, int lane, int cg, int half,
                                           f32x16& o0, f32x16& o1) {
    f32x16 acc0 = {}, acc1 = {};
#pragma unroll
    for (int c = 0; c < NC; ++c) {
        const int gc = BASE + c;
        short8 gB;
        if (gc + 2 < NCH) gB = gsrc[(size_t)(gc + 2) * 512 + tid];
        const short8* buf = wb + (gc & 1) * 512;
        __builtin_amdgcn_s_setprio(1);
#pragma unroll
        for (int kl = 0; kl < 2; ++kl) {
            const int kt = c * 2 + kl;
            half8 a = FROM_H
                ? __builtin_bit_cast(half8, *(const short8*)&hsr[lane & 31][kt * 16 + half])
                : a1[kt];
            half8 b0 = __builtin_bit_cast(half8, buf[(kl * 4 + cg * 2 + 0) * 64 + lane]);
            half8 b1 = __builtin_bit_cast(half8, buf[(kl * 4 + cg * 2 + 1) * 64 + lane]);
            acc0 = MFMA16(a, b0, acc0);
            acc1 = MFMA16(a, b1, acc1);
        }
        __builtin_amdgcn_s_setprio(0);
        if (gc + 1 < NCH) wb[((gc + 1) & 1) * 512 + tid] = gA;
        barrier_lgkm();
        if (gc + 2 < NCH) gA = gB;
    }
    o0 = acc0; o1 = acc1;
}

__device__ __forceinline__ void hwrite(short (*hsr)[136], const f32x16& a0, const f32x16& a1v,
                                       const float* __restrict__ b0, int lane, int cg) {
#pragma unroll
    for (int ct = 0; ct < 2; ++ct) {
        const int col = cg * 64 + ct * 32 + (lane & 31);
        const float bv = b0[col];
        f32x16 a = ct ? a1v : a0;
#pragma unroll
        for (int rp = 0; rp < 8; ++rp) {
            const int reg = rp * 2;
            const int row = (reg & 3) + 8 * (reg >> 2) + 4 * (lane >> 5);
            const unsigned pr = pkh(fmaxf(a[reg] + bv, 0.f), fmaxf(a[reg + 1] + bv, 0.f));
            hsr[row][col]     = (short)(pr & 0xFFFF);
            hsr[row + 1][col] = (short)(pr >> 16);
        }
    }
}

__global__ __launch_bounds__(512, 4)
void edge_mfma(int ii,
               const float* __restrict__ b0m, const float* __restrict__ b1m,
               const float* __restrict__ b0a, const float* __restrict__ b1a,
               float* __restrict__ state_msg) {
    // pool: wb 16384 | hs 4x32x136x2 = 34816 | sdst 512  = 51712 B
    // epilogue overlays [0, 33792) as f32 vt[64][132] (2 passes); wb+hs dead by then
    __shared__ __align__(16) char pool[51712];
    short8* wb = (short8*)pool;
    short (*hs)[32][136] = (short(*)[32][136])(pool + 16384);
    int* sdst = (int*)(pool + 51200);

    const int tid  = threadIdx.x;
    const int lane = tid & 63;
    const int w    = tid >> 6;          // 0..7
    const int rt   = w >> 1;            // 0..3  (32-edge group)
    const int cg   = w & 1;             // 0..1  (64-col group)
    const int e0   = blockIdx.x * TE;

    if (tid < TE) sdst[tid] = g_sdst[e0 + tid];

    // ---- gather A1 fragments from fp16 shadow (sorted edge order)
    const int er   = e0 + rt * 32 + (lane & 31);
    const int half = (lane >> 5) << 3;
    const int s  = g_ssrc[er];
    const int d2 = g_sdst[er];
    const short* srow = g_sbf + (size_t)s  * D;
    const short* drow = g_sbf + (size_t)d2 * D;
    half8 a1[12];
#pragma unroll
    for (int kt = 0; kt < 8; ++kt) {
        const int k0 = kt * 16 + half;
        half8 sv = __builtin_bit_cast(half8, *(const short8*)(srow + k0));
        half8 dv = __builtin_bit_cast(half8, *(const short8*)(drow + k0));
        a1[kt] = sv - dv;                      // 4x v_pk_add_f16
    }
#pragma unroll
    for (int kt = 8; kt < 12; ++kt)
        a1[kt] = __builtin_bit_cast(half8, *(const short8*)(g_efdf + (size_t)er * 64 + (kt - 8) * 16 + half));

    const short8* gsrc = (const short8*)(g_wp + (size_t)ii * 81920);

    // prologue: stage chunk 0 to LDS; hold chunk 1 in regs
    wb[tid] = gsrc[tid];
    short8 gA = gsrc[512 + tid];
    barrier_lgkm();

    f32x16 t0, t1, m0, m1, c0, c1;
    gemm_phase<0, 6, false>(gsrc, wb, gA, a1, hs[rt], tid, lane, cg, half, t0, t1); // msg GEMM1 (0-5)
    hwrite(hs[rt], t0, t1, b0m, lane, cg);
    barrier_lgkm();
    gemm_phase<6, 4, true>(gsrc, wb, gA, a1, hs[rt], tid, lane, cg, half, m0, m1);  // msg GEMM2 (6-9)

    // pack (msg + bias) to fp16 pairs: frees 16 regs across the att path
    unsigned mb[16];
#pragma unroll
    for (int ct = 0; ct < 2; ++ct) {
        const float bm = b1m[cg * 64 + ct * 32 + (lane & 31)];
        f32x16 mv = ct ? m1 : m0;
#pragma unroll
        for (int rp = 0; rp < 8; ++rp)
            mb[ct * 8 + rp] = pkh(mv[rp * 2] + bm, mv[rp * 2 + 1] + bm);
    }

    gemm_phase<10, 6, false>(gsrc, wb, gA, a1, hs[rt], tid, lane, cg, half, t0, t1); // att GEMM1 (10-15)
    hwrite(hs[rt], t0, t1, b0a, lane, cg);
    barrier_lgkm();
    gemm_phase<16, 4, true>(gsrc, wb, gA, a1, hs[rt], tid, lane, cg, half, c0, c1);  // att GEMM2 (16-19)

    // ---- 2-pass combine (f32 vt overlay) + segmented reduction over sorted runs
    float (*vt)[132] = (float(*)[132])pool;
    const int colr = tid & 127;
    const int sub  = tid >> 7;          // 0..3
#pragma unroll
    for (int pass = 0; pass < 2; ++pass) {
        if ((rt >> 1) == pass) {
#pragma unroll
            for (int ct = 0; ct < 2; ++ct) {
                const int col = cg * 64 + ct * 32 + (lane & 31);
                const float ba = b1a[col];
                f32x16 av = ct ? c1 : c0;
#pragma unroll
                for (int rp = 0; rp < 8; ++rp) {
                    const int reg = rp * 2;
                    const unsigned u = mb[ct * 8 + rp];
                    const int row = (rt & 1) * 32 + (reg & 3) + 8 * (reg >> 2) + 4 * (lane >> 5);
                    vt[row][col]     = h2f((short)(u & 0xFFFF)) * sigm(av[reg] + ba);
                    vt[row + 1][col] = h2f((short)(u >> 16))    * sigm(av[reg + 1] + ba);
                }
            }
        }
        barrier_lgkm();
        const int gbase = pass * 64 + sub * 16;
        float run = 0.f;
        int cur = sdst[gbase];
#pragma unroll 4
        for (int r = 0; r < 16; ++r) {
            const int dd = sdst[gbase + r];
            if (dd != cur) {
                atomicAdd(state_msg + (size_t)cur * D + colr, run);
                run = 0.f; cur = dd;
            }
            run += vt[sub * 16 + r][colr];
        }
        atomicAdd(state_msg + (size_t)cur * D + colr, run);
        barrier_lgkm();   // atomics may stay in flight; only vt/LDS ordering needed
    }
}

// ---------------- LSTM: bf16 MFMA; non-last layer also writes relu'd state,
//                  fp16 shadow, and zeros its state_msg rows ----------------
__global__ __launch_bounds__(256, 4)
void lstm_mfma(float* __restrict__ x, float* __restrict__ hbuf, float* __restrict__ cbuf,
               int ii, int last,
               const float* __restrict__ bih, const float* __restrict__ bhh) {
    __shared__ short8 wb[2048];
    const int tid  = threadIdx.x;
    const int lane = tid & 63;
    const int w    = tid >> 6;
    const int n0   = blockIdx.x * 32;
    const int half = (lane >> 5) << 3;
    const int nl   = lane & 31;
    const int nld  = min(n0 + nl, N - 1);

    const short8* gsrc = (const short8*)(g_lw + (size_t)ii * 131072);

    {
        short8 g[4];
#pragma unroll
        for (int i = 0; i < 4; ++i) g[i] = gsrc[tid + i * 256];
#pragma unroll
        for (int i = 0; i < 4; ++i) wb[tid + i * 256] = g[i];
        __syncthreads();
    }

    f32x16 acc[4] = {};
#pragma unroll
    for (int kt = 0; kt < 16; ++kt) {
        const float* srow = (kt < 8) ? (x + (size_t)nld * D + kt * 16 + half)
                                     : (hbuf + (size_t)nld * D + (kt - 8) * 16 + half);
        float4 u0 = *(const float4*)(srow);
        float4 u1 = *(const float4*)(srow + 4);
        short8 a;
        unsigned* ap = (unsigned*)&a;
        ap[0] = pk2(u0.x, u0.y); ap[1] = pk2(u0.z, u0.w);
        ap[2] = pk2(u1.x, u1.y); ap[3] = pk2(u1.z, u1.w);

        short8 g[4];
        if (kt + 1 < 16) {
            const short8* p = gsrc + (size_t)(kt + 1) * 1024;
#pragma unroll
            for (int i = 0; i < 4; ++i) g[i] = p[tid + i * 256];
        }
        const short8* buf = wb + (kt & 1) * 1024;
        __builtin_amdgcn_s_setprio(1);
#pragma unroll
        for (int q = 0; q < 4; ++q) {
            short8 b = buf[(q * 4 + w) * 64 + lane];
            acc[q] = MFMABF(a, b, acc[q]);
        }
        __builtin_amdgcn_s_setprio(0);
        if (kt + 1 < 16) {
            short8* d = wb + ((kt + 1) & 1) * 1024;
#pragma unroll
            for (int i = 0; i < 4; ++i) d[tid + i * 256] = g[i];
        }
        __syncthreads();   // final iteration: all x/h reads in block are complete after this
    }

    const int col = (w << 5) + nl;
    const float bi = bih[col]       + bhh[col];
    const float bf = bih[128 + col] + bhh[128 + col];
    const float bg = bih[256 + col] + bhh[256 + col];
    const float bo = bih[384 + col] + bhh[384 + col];
#pragma unroll
    for (int reg = 0; reg < 16; ++reg) {
        const int nn = (reg & 3) + 8 * (reg >> 2) + 4 * (lane >> 5);
        const int n = n0 + nn;
        if (n < N) {
            const float gi = acc[0][reg] + bi;
            const float gf = acc[1][reg] + bf;
            const float gg = acc[2][reg] + bg;
            const float go = acc[3][reg] + bo;
            float* cp = cbuf + (size_t)n * D + col;
            const float c2 = sigm(gf) * (*cp) + sigm(gi) * tanhf(gg);
            const float h2 = sigm(go) * tanhf(c2);
            *cp = c2;
            const float ho = last ? h2 : fmaxf(h2, 0.f);
            hbuf[(size_t)n * D + col] = ho;
            if (!last) g_sbf[(size_t)n * D + col] = f2h(ho);
        }
    }

    // non-last: zero this block's state_msg rows for the next layer
    if (!last) {
        float4* xr = (float4*)(x + (size_t)n0 * D);
        const float4 z = make_float4(0.f, 0.f, 0.f, 0.f);
#pragma unroll
        for (int i = 0; i < 4; ++i) {
            const int idx = tid + i * 256;               // 0..1023 = 32 nodes x 32 float4
            if (n0 + (idx >> 5) < N) xr[idx] = z;
        }
    }
}

extern "C" void kernel_launch(void* const* d_in, const int* in_sizes, int n_in,
                              void* d_out, int out_size, void* d_ws, size_t ws_size,
                              hipStream_t stream) {
    const float* node_feat   = (const float*)d_in[0];
    const float* node_feat_c = (const float*)d_in[1];
    const int*   edge        = (const int*)d_in[2];
    const float* edge_feat   = (const float*)d_in[3];
    const float* dist_feat   = (const float*)d_in[4];
    const float* msg_w0 = (const float*)d_in[5];
    const float* msg_b0 = (const float*)d_in[6];
    const float* msg_w1 = (const float*)d_in[7];
    const float* msg_b1 = (const float*)d_in[8];
    const float* att_w0 = (const float*)d_in[9];
    const float* att_b0 = (const float*)d_in[10];
    const float* att_w1 = (const float*)d_in[11];
    const float* att_b1 = (const float*)d_in[12];
    const float* lstm_wih = (const float*)d_in[13];
    const float* lstm_whh = (const float*)d_in[14];
    const float* lstm_bih = (const float*)d_in[15];
    const float* lstm_bhh = (const float*)d_in[16];

    float* state     = (float*)d_out;
    float* state_c   = (float*)d_ws;
    float* state_msg = (float*)d_ws + (size_t)N * D;

    // fused prep: zero hist + pack edge/LSTM weights (independent of sort)
    prep_static<<<1024, 256, 0, stream>>>(msg_w0, att_w0, msg_w1, att_w1, lstm_wih, lstm_whh);

    // sort edges by dst (per call; edge list static across layers); scatter also packs ef/df
    hist_kernel<<<(M + 255) / 256, 256, 0, stream>>>(edge);
    scanA_kernel<<<NBLK, 256, 0, stream>>>();
    scanB_kernel<<<1, 256, 0, stream>>>();
    scanC_kernel<<<NBLK, 256, 0, stream>>>();
    scatter_kernel<<<(M + 255) / 256, 256, 0, stream>>>(edge, edge_feat, dist_feat);

    init_kernel<<<2048, 256, 0, stream>>>((const float4*)node_feat, (const float4*)node_feat_c,
                                          (float4*)state, (float4*)state_c, (float4*)state_msg);

    for (int ii = 0; ii < 2; ++ii) {
        edge_mfma<<<M / TE, 512, 0, stream>>>(
            ii,
            msg_b0 + (size_t)ii * D, msg_b1 + (size_t)ii * D,
            att_b0 + (size_t)ii * D, att_b1 + (size_t)ii * D,
            state_msg);

        lstm_mfma<<<(N + 31) / 32, 256, 0, stream>>>(
            state_msg, state, state_c, ii, (ii == 1) ? 1 : 0,
            lstm_bih + (size_t)ii * 4 * D, lstm_bhh + (size_t)ii * 4 * D);
    }
}